// Round 18
// baseline (252.626 us; speedup 1.0000x reference)
//
#include <hip/hip_runtime.h>
#include <hip/hip_bf16.h>
#include <hip/hip_fp8.h>
#include <stdint.h>

#define NTOK 196
#define NB   64
#define CCH  512
#define HID  2048
#define MTOT (NB * NTOK)   // 12544

typedef __attribute__((ext_vector_type(8))) short  short8v;
typedef __attribute__((ext_vector_type(4))) float  float4v;
typedef __attribute__((ext_vector_type(2))) int    int2v;

// ---------------- helpers ----------------

__device__ __forceinline__ void mfma_fp8(float4v& d, int2v a, int2v b) {
  asm("v_mfma_f32_16x16x32_fp8_fp8 %0, %1, %2, %0" : "+v"(d) : "v"(a), "v"(b));
}

__device__ __forceinline__ void gload_lds16(const void* gsrc, void* ldst) {
  __builtin_amdgcn_global_load_lds(
      (const __attribute__((address_space(1))) unsigned int*)gsrc,
      (__attribute__((address_space(3))) unsigned int*)ldst, 16, 0, 0);
}

__device__ __forceinline__ int swz4(int r) { return (r ^ (r >> 2)) & 3; }

// hardware packed fp8 conversion: byte0 = fp8(a), byte1 = fp8(b)
__device__ __forceinline__ uint32_t cvt2_fp8(float a, float b) {
  uint32_t d;
  asm("v_cvt_pk_fp8_f32 %0, %1, %2" : "=v"(d) : "v"(a), "v"(b));
  return d;
}

// ---------------- prep: BN constants ----------------

__global__ void prep_consts(const float* __restrict__ bn_g, const float* __restrict__ bn_b,
                            const float* __restrict__ bn_m, const float* __restrict__ bn_v,
                            const float* __restrict__ fbn_g, const float* __restrict__ fbn_b,
                            const float* __restrict__ fbn_m, const float* __restrict__ fbn_v,
                            float* __restrict__ cst) {
  int c = blockIdx.x * blockDim.x + threadIdx.x;
  if (c < CCH) {
    float i1 = bn_g[c] * rsqrtf(bn_v[c] + 1e-5f);
    cst[c] = i1;
    cst[512 + c] = bn_b[c] - bn_m[c] * i1;
    float i2 = fbn_g[c] * rsqrtf(fbn_v[c] + 1e-5f);
    cst[1024 + c] = i2;
    cst[1536 + c] = fbn_b[c] - fbn_m[c] * i2;
  }
}

// ---------------- weights fp32 -> fp8 e4m3, x16 ----------------

__global__ void cvt_weights(const float* __restrict__ qkv_w, const float* __restrict__ proj_w,
                            const float* __restrict__ fc1_w, const float* __restrict__ fc2_w,
                            uint8_t* __restrict__ qkvb, uint8_t* __restrict__ projb,
                            uint8_t* __restrict__ fc1b, uint8_t* __restrict__ fc2b) {
  int i4 = blockIdx.x * blockDim.x + threadIdx.x;    // unit = 4 floats
  const int nq = 1536 * 512 / 4;
  const int np = 512 * 512 / 4;
  const int n1 = 2048 * 512 / 4;
  const float* src;
  uint8_t* dst;
  int k;
  if (i4 < nq)                { src = qkv_w;  dst = qkvb;  k = i4; }
  else if (i4 < nq + np)      { src = proj_w; dst = projb; k = i4 - nq; }
  else if (i4 < nq + np + n1) { src = fc1_w;  dst = fc1b;  k = i4 - nq - np; }
  else                        { src = fc2_w;  dst = fc2b;  k = i4 - nq - np - n1; }
  float4v v = *(const float4v*)(src + 4 * (size_t)k);
  uint32_t w0 = cvt2_fp8(v[0] * 16.0f, v[1] * 16.0f);
  uint32_t w1 = cvt2_fp8(v[2] * 16.0f, v[3] * 16.0f);
  *(uint16_t*)(dst + 4 * (size_t)k)     = (uint16_t)w0;
  *(uint16_t*)(dst + 4 * (size_t)k + 2) = (uint16_t)w1;
}

// ---------------- transpose NCHW fp32 -> token-major: fp8 (BN'd) + bf16 (raw) ----------------

__global__ __launch_bounds__(256) void transpose_x(
    const float* __restrict__ x, uint8_t* __restrict__ xnt8,
    __hip_bfloat16* __restrict__ xt, const float* __restrict__ cst) {
  __shared__ float tile[32][33];
  const int n0 = blockIdx.x * 32;
  const int c0 = blockIdx.y * 32;
  const int b  = blockIdx.z;
  const int j = threadIdx.x & 31, i = threadIdx.x >> 5;
  #pragma unroll
  for (int p = 0; p < 4; ++p) {
    int cc = c0 + i + p * 8;
    int n = n0 + j;
    if (n < NTOK) tile[i + p * 8][j] = x[((size_t)b * CCH + cc) * NTOK + n];
  }
  __syncthreads();
  const float s = cst[c0 + j], t = cst[512 + c0 + j];
  float bn[4];
  size_t off[4];
  bool ok[4];
  #pragma unroll
  for (int p = 0; p < 4; ++p) {
    int n = n0 + i + p * 8;
    int cc = c0 + j;
    ok[p] = (n < NTOK);
    if (ok[p]) {
      float raw = tile[j][i + p * 8];
      size_t o = ((size_t)b * NTOK + n) * CCH + cc;
      xt[o] = __float2bfloat16(raw);
      bn[p] = raw * s + t;
      off[p] = o;
    }
  }
  uint32_t w0 = cvt2_fp8(bn[0], bn[1]);
  uint32_t w1 = cvt2_fp8(bn[2], bn[3]);
  if (ok[0]) xnt8[off[0]] = (uint8_t)w0;
  if (ok[1]) xnt8[off[1]] = (uint8_t)(w0 >> 8);
  if (ok[2]) xnt8[off[2]] = (uint8_t)w1;
  if (ok[3]) xnt8[off[3]] = (uint8_t)(w1 >> 8);
}

// ---------------- one-shot-LDS fp8 GEMM: C[M,N] = (A[M,K]*B[N,K]^T)/16 ----------------
// 128x128 tile, 4 waves (2x2), per-wave 64x64. Per 512-K chunk: stage FULL A-tile
// (64KB) + B-tile (64KB) into LDS (512B rows, 32x16B-chunk XOR swizzle), ONE
// __syncthreads, then 16 K-iterations of pure LDS->MFMA with ZERO synchronization.
// EPI: 0 = qkv: fp8 head-major [sel][h][b][tok][32]
//      1 = proj: x1t = xt + ls1*(v/16+bias)
//      2 = fc1: gelu(v/16+bias)->fp8  3 = fc2: out = x1t + ls2*(v/16+bias) -> NCHW fp32

template<int EPI>
__global__ __launch_bounds__(256, 1) void gemm1s(
    const uint8_t* __restrict__ A, const uint8_t* __restrict__ Bw,
    int N, int K, int NY,
    __hip_bfloat16* __restrict__ outb, uint8_t* __restrict__ out8,
    float* __restrict__ outf,
    const float* __restrict__ bias, const float* __restrict__ ls,
    const __hip_bfloat16* __restrict__ resid) {
  __shared__ char lds[131072];   // A [0,64K) + B [64K,128K)
  const int tid  = threadIdx.x;
  const int lane = tid & 63;
  const int wave = tid >> 6;
  const int g    = lane >> 4;
  const int l15  = lane & 15;

  // bijective XCD swizzle, by-fast linearization (nwg % 8 == 0 for all grids)
  const int q    = (int)gridDim.x >> 3;
  const int orig = blockIdx.x;
  const int wgid = (orig & 7) * q + (orig >> 3);
  const int bx = wgid / NY;
  const int by = wgid - bx * NY;

  const int m0 = bx * 128;
  const int n0 = by * 128;
  const int wm = (wave >> 1) * 64;
  const int wn = (wave & 1) * 64;
  const int KCH = K >> 9;               // 512-K chunks (1 for K=512, 4 for K=2048)

  float4v acc[4][4] = {};

  // stage one 512-K chunk of A and B (64KB each); verified 32-chunk XOR pair (R15 sA)
  auto stageAB = [&](int ch) {
    const int kb = ch << 9;
    #pragma unroll
    for (int u = 0; u < 16; ++u) {
      int L = u * 4096 + tid * 16;
      int r = L >> 9;                   // 0..127
      int pc = (L >> 4) & 31;
      int lc = pc ^ (r & 31);
      gload_lds16(A + (size_t)(m0 + r) * K + kb + lc * 16, lds + L);
    }
    #pragma unroll
    for (int u = 0; u < 16; ++u) {
      int L = u * 4096 + tid * 16;
      int r = L >> 9;
      int pc = (L >> 4) & 31;
      int lc = pc ^ (r & 31);
      gload_lds16(Bw + (size_t)(n0 + r) * K + kb + lc * 16, lds + 65536 + L);
    }
  };

  #pragma unroll 1
  for (int ch = 0; ch < KCH; ++ch) {
    if (ch) __syncthreads();            // all waves done reading previous chunk
    stageAB(ch);
    __syncthreads();                    // drains vmcnt: chunk fully resident
    // ---- 16 K-iterations, barrier-free, compiler-scheduled lgkmcnt pipeline ----
    #pragma unroll
    for (int kt = 0; kt < 16; ++kt) {
      const int c16 = kt * 2 + (g >> 1);     // 16B-chunk index within 512B row
      int2v av[4], bv[4];
      #pragma unroll
      for (int f = 0; f < 4; ++f) {
        int r = wm + f * 16 + l15;
        int pc = c16 ^ (r & 31);
        av[f] = *(const int2v*)(lds + r * 512 + pc * 16 + (g & 1) * 8);
      }
      #pragma unroll
      for (int j = 0; j < 4; ++j) {
        int r = wn + j * 16 + l15;
        int pc = c16 ^ (r & 31);
        bv[j] = *(const int2v*)(lds + 65536 + r * 512 + pc * 16 + (g & 1) * 8);
      }
      #pragma unroll
      for (int i = 0; i < 4; ++i)
        #pragma unroll
        for (int j = 0; j < 4; ++j)
          mfma_fp8(acc[i][j], av[i], bv[j]);
    }
  }
  asm volatile("s_nop 7\n\ts_nop 7");

  const float RS = 0.0625f;                // undo weight x16

  if (EPI == 0) {
    // fp8 head-major: [sel(3)][h(16)][b(64)][tok(196)][d(32)]
    #pragma unroll
    for (int i = 0; i < 4; ++i)
      #pragma unroll
      for (int j = 0; j < 4; ++j)
        #pragma unroll
        for (int r = 0; r < 4; r += 2) {
          int m = m0 + wm + i * 16 + (g << 2) + r;
          int n = n0 + wn + j * 16 + l15;
          int bb = m / NTOK, tok = m - bb * NTOK;
          int bb2 = (m + 1) / NTOK, tok2 = (m + 1) - bb2 * NTOK;
          int sel = n >> 9, hh = (n >> 5) & 15, d = n & 31;
          uint32_t w = cvt2_fp8(acc[i][j][r] * RS, acc[i][j][r + 1] * RS);
          out8[(((size_t)(sel * 16 + hh) * NB + bb) * NTOK + tok) * 32 + d]  = (uint8_t)w;
          out8[(((size_t)(sel * 16 + hh) * NB + bb2) * NTOK + tok2) * 32 + d] = (uint8_t)(w >> 8);
        }
  } else if (EPI == 2) {
    #pragma unroll
    for (int i = 0; i < 4; ++i)
      #pragma unroll
      for (int j = 0; j < 4; ++j)
        #pragma unroll
        for (int r = 0; r < 4; r += 2) {
          int m = m0 + wm + i * 16 + (g << 2) + r;
          int n = n0 + wn + j * 16 + l15;
          float z0 = acc[i][j][r] * RS + bias[n];
          float z1 = acc[i][j][r + 1] * RS + bias[n];
          float g0 = z0 / (1.0f + __expf(-1.702f * z0));
          float g1 = z1 / (1.0f + __expf(-1.702f * z1));
          uint32_t w = cvt2_fp8(g0, g1);
          out8[(size_t)m * N + n]       = (uint8_t)w;
          out8[(size_t)(m + 1) * N + n] = (uint8_t)(w >> 8);
        }
  } else if (EPI == 1) {
    #pragma unroll
    for (int i = 0; i < 4; ++i)
      #pragma unroll
      for (int j = 0; j < 4; ++j)
        #pragma unroll
        for (int r = 0; r < 4; ++r) {
          int m = m0 + wm + i * 16 + (g << 2) + r;
          int n = n0 + wn + j * 16 + l15;
          float v = acc[i][j][r] * RS + bias[n];
          v = __bfloat162float(resid[(size_t)m * CCH + n]) + ls[n] * v;
          outb[(size_t)m * CCH + n] = __float2bfloat16(v);
        }
  } else {   // EPI == 3 : epilogue + in-LDS transpose -> NCHW fp32
    float* LT = (float*)lds;   // [64][129] fp32 = 33KB
    #pragma unroll 1
    for (int hh = 0; hh < 2; ++hh) {
      __syncthreads();
      if ((wn >> 6) == hh) {
        #pragma unroll
        for (int i = 0; i < 4; ++i)
          #pragma unroll
          for (int j = 0; j < 4; ++j)
            #pragma unroll
            for (int r = 0; r < 4; ++r) {
              int ml = wm + i * 16 + (g << 2) + r;
              int nl = j * 16 + l15;
              int n = n0 + wn + nl;
              float v = acc[i][j][r] * RS + bias[n];
              v = __bfloat162float(resid[(size_t)(m0 + ml) * CCH + n]) + ls[n] * v;
              LT[nl * 129 + ml] = v;
            }
      }
      __syncthreads();
      {
        int ml0 = lane << 1;
        int mg = m0 + ml0;
        int bb0 = mg / NTOK;
        int tt0 = mg - bb0 * NTOK;
        int bb1 = (mg + 1) / NTOK;
        int tt1 = (mg + 1) - bb1 * NTOK;
        size_t base0 = (size_t)bb0 * (CCH * NTOK) + tt0;
        size_t base1 = (size_t)bb1 * (CCH * NTOK) + tt1;
        #pragma unroll
        for (int u = 0; u < 16; ++u) {
          int cr = wave * 16 + u;
          int cg = n0 + hh * 64 + cr;
          float v0 = LT[cr * 129 + ml0];
          float v1 = LT[cr * 129 + ml0 + 1];
          outf[base0 + (size_t)cg * NTOK] = v0;
          outf[base1 + (size_t)cg * NTOK] = v1;
        }
      }
    }
  }
}

// ---------------- attention: fp8 end-to-end, head-major input ----------------

__global__ __launch_bounds__(256, 3) void attn_kernel(
    const uint8_t* __restrict__ qkv8, uint8_t* __restrict__ o_t8) {
  __shared__ char sQ[208 * 48];
  __shared__ char sK[224 * 48];
  __shared__ char sV[32 * 240];
  __shared__ char sP[4][16 * 232];
  const int tid  = threadIdx.x;
  const int lane = tid & 63;
  const int wave = tid >> 6;
  const int b = blockIdx.x >> 4;
  const int h = blockIdx.x & 15;
  const size_t CHB = 6272;
  const uint8_t* Qg = qkv8 + ((size_t)(0 * 16 + h) * NB + b) * CHB;
  const uint8_t* Kg = qkv8 + ((size_t)(1 * 16 + h) * NB + b) * CHB;
  const uint8_t* Vg = qkv8 + ((size_t)(2 * 16 + h) * NB + b) * CHB;

  for (int i = tid; i < 144; i += 256) {
    int r = i / 12, w = i % 12;
    ((uint32_t*)(sQ + (196 + r) * 48))[w] = 0u;
  }
  for (int i = tid; i < 336; i += 256) {
    int r = i / 12, w = i % 12;
    ((uint32_t*)(sK + (196 + r) * 48))[w] = 0u;
  }
  for (int i = tid; i < 352; i += 256) {
    int d = i / 11, w = i % 11;
    ((uint32_t*)(sV + d * 240 + 196))[w] = 0u;
  }

  for (int c = tid; c < 392; c += 256) {
    int row = c >> 1, hf = c & 1;
    uint4 vq = *(const uint4*)(Qg + c * 16);
    *(uint4*)(sQ + row * 48 + hf * 16) = vq;
    uint4 vk = *(const uint4*)(Kg + c * 16);
    *(uint4*)(sK + row * 48 + hf * 16) = vk;
  }
  for (int u = tid; u < 784; u += 256) {
    int row = u >> 2, d0 = (u & 3) * 8;
    uint64_t w = *(const uint64_t*)(Vg + (size_t)u * 8);
    #pragma unroll
    for (int e = 0; e < 8; ++e)
      sV[(d0 + e) * 240 + row] = (char)(w >> (8 * e));
  }
  __syncthreads();

  const float scale = 0.17677669529663687f;
  char* Pw = sP[wave];
  const int g = lane >> 4;

  for (int mt = wave; mt < 13; mt += 4) {
    int qrow = mt * 16 + (lane & 15);
    int2v aq = *(const int2v*)(sQ + qrow * 48 + g * 8);

    float4v s[14];
    #pragma unroll
    for (int nt = 0; nt < 14; ++nt) {
      int krow = nt * 16 + (lane & 15);
      int2v bk = *(const int2v*)(sK + krow * 48 + g * 8);
      s[nt] = float4v{0.f, 0.f, 0.f, 0.f};
      mfma_fp8(s[nt], aq, bk);
    }
    asm volatile("s_nop 7\n\ts_nop 7");

    float mx[4] = {-INFINITY, -INFINITY, -INFINITY, -INFINITY};
    #pragma unroll
    for (int nt = 0; nt < 14; ++nt) {
      bool valid = (nt * 16 + (lane & 15)) < NTOK;
      #pragma unroll
      for (int r = 0; r < 4; ++r) {
        float v = valid ? s[nt][r] * scale : -INFINITY;
        s[nt][r] = v;
        mx[r] = fmaxf(mx[r], v);
      }
    }
    #pragma unroll
    for (int off = 1; off < 16; off <<= 1) {
      #pragma unroll
      for (int r = 0; r < 4; ++r) mx[r] = fmaxf(mx[r], __shfl_xor(mx[r], off));
    }
    float sum[4] = {0.f, 0.f, 0.f, 0.f};
    #pragma unroll
    for (int nt = 0; nt < 14; ++nt) {
      #pragma unroll
      for (int r = 0; r < 4; ++r) {
        float e = __expf(s[nt][r] - mx[r]);
        s[nt][r] = e;
        sum[r] += e;
      }
    }
    #pragma unroll
    for (int off = 1; off < 16; off <<= 1) {
      #pragma unroll
      for (int r = 0; r < 4; ++r) sum[r] += __shfl_xor(sum[r], off);
    }
    float rs[4];
    #pragma unroll
    for (int r = 0; r < 4; ++r) rs[r] = 1.0f / sum[r];

    #pragma unroll
    for (int nt = 0; nt < 14; ++nt) {
      int col = nt * 16 + (lane & 15);
      #pragma unroll
      for (int r = 0; r < 4; r += 2) {
        int prow = ((lane >> 4) << 2) + r;
        uint32_t w = cvt2_fp8(s[nt][r], s[nt][r + 1]);
        *(uint8_t*)(Pw + prow * 232 + col)       = (uint8_t)w;
        *(uint8_t*)(Pw + (prow + 1) * 232 + col) = (uint8_t)(w >> 8);
      }
    }

    float4v o0 = float4v{0.f, 0.f, 0.f, 0.f};
    float4v o1 = float4v{0.f, 0.f, 0.f, 0.f};
    #pragma unroll
    for (int ks = 0; ks < 7; ++ks) {
      int2v pa = *(const int2v*)(Pw + (lane & 15) * 232 + ks * 32 + g * 8);
      int2v v0 = *(const int2v*)(sV + (lane & 15) * 240 + ks * 32 + g * 8);
      int2v v1 = *(const int2v*)(sV + (16 + (lane & 15)) * 240 + ks * 32 + g * 8);
      mfma_fp8(o0, pa, v0);
      mfma_fp8(o1, pa, v1);
    }
    asm volatile("s_nop 7\n\ts_nop 7");

    #pragma unroll
    for (int r = 0; r < 4; ++r) {
      int trow = mt * 16 + ((lane >> 4) << 2) + r;
      if (trow < NTOK) {
        size_t ob = ((size_t)b * NTOK + trow) * CCH + h * 32 + (lane & 15);
        uint32_t w = cvt2_fp8(o0[r] * rs[r], o1[r] * rs[r]);
        o_t8[ob]      = (uint8_t)w;
        o_t8[ob + 16] = (uint8_t)(w >> 8);
      }
    }
  }
}

// ---------------- depthwise 7x7 conv, token-major (+BN in, +fBN out, fp8 out) ----------------

__global__ __launch_bounds__(448) void dwconv_tm(
    const __hip_bfloat16* __restrict__ x1t, const float* __restrict__ dw_w,
    const float* __restrict__ cst, uint8_t* __restrict__ yt8) {
  __shared__ float img[196][32];
  __shared__ float wgt[49][32];
  const int tid = threadIdx.x;
  const int b  = blockIdx.x >> 4;
  const int cb = (blockIdx.x & 15) * 32;
  const int c  = tid & 31;
  const int gc = cb + c;
  const float s = cst[gc], t0 = cst[512 + gc];
  #pragma unroll
  for (int k = 0; k < 14; ++k) {
    int p = (tid >> 5) + k * 14;
    img[p][c] = __bfloat162float(x1t[((size_t)b * NTOK + p) * CCH + gc]) * s + t0;
  }
  for (int i = tid; i < 49 * 32; i += 448) {
    int tap = i >> 5, cc = i & 31;
    wgt[tap][cc] = dw_w[(cb + cc) * 49 + tap];
  }
  __syncthreads();

  const int px = tid >> 5;
  float out[14];
  #pragma unroll
  for (int i = 0; i < 14; ++i) out[i] = 0.f;
  #pragma unroll 1
  for (int row = 0; row < 14; ++row) {
    float v[7];
    #pragma unroll
    for (int dx = 0; dx < 7; ++dx) {
      int ix = px + dx - 3;
      v[dx] = ((unsigned)ix < 14u) ? img[row * 14 + ix][c] : 0.f;
    }
    #pragma unroll
    for (int kk = 0; kk < 7; ++kk) {
      int py = row + 3 - kk;
      if (py >= 0 && py < 14) {
        float hsum = 0.f;
        #pragma unroll
        for (int dx = 0; dx < 7; ++dx) hsum = fmaf(v[dx], wgt[kk * 7 + dx][c], hsum);
        out[py] += hsum;
      }
    }
  }
  const float fs = cst[1024 + gc], ft = cst[1536 + gc];
  #pragma unroll
  for (int py = 0; py < 14; py += 2) {
    uint32_t w = cvt2_fp8(out[py] * fs + ft, out[py + 1] * fs + ft);
    yt8[((size_t)b * NTOK + py * 14 + px) * CCH + gc]       = (uint8_t)w;
    yt8[((size_t)b * NTOK + (py + 1) * 14 + px) * CCH + gc] = (uint8_t)(w >> 8);
  }
}

// ---------------- launch ----------------

extern "C" void kernel_launch(void* const* d_in, const int* in_sizes, int n_in,
                              void* d_out, int out_size, void* d_ws, size_t ws_size,
                              hipStream_t stream) {
  const float* x      = (const float*)d_in[0];
  const float* bn_g   = (const float*)d_in[1];
  const float* bn_b   = (const float*)d_in[2];
  const float* bn_m   = (const float*)d_in[3];
  const float* bn_v   = (const float*)d_in[4];
  const float* qkv_w  = (const float*)d_in[5];
  const float* proj_w = (const float*)d_in[6];
  const float* proj_b = (const float*)d_in[7];
  const float* dw_w   = (const float*)d_in[8];
  const float* fbn_g  = (const float*)d_in[9];
  const float* fbn_b  = (const float*)d_in[10];
  const float* fbn_m  = (const float*)d_in[11];
  const float* fbn_v  = (const float*)d_in[12];
  const float* fc1_w  = (const float*)d_in[13];
  const float* fc1_b  = (const float*)d_in[14];
  const float* fc2_w  = (const float*)d_in[15];
  const float* fc2_b  = (const float*)d_in[16];
  const float* ls1    = (const float*)d_in[17];
  const float* ls2    = (const float*)d_in[18];

  char* ws = (char*)d_ws;
  float* cst             = (float*)ws;                        // 8 KB
  uint8_t* qkvb8         = (uint8_t*)(ws + 32768);            // 768 KB
  uint8_t* projb8        = (uint8_t*)(ws + 819200);           // 256 KB
  uint8_t* fc1b8         = (uint8_t*)(ws + 1081344);          // 1 MB
  uint8_t* fc2b8         = (uint8_t*)(ws + 2129920);          // 1 MB
  uint8_t* xnt8          = (uint8_t*)(ws + 3178496);          // 6.4 MB (fp8 BN'd x)
  __hip_bfloat16* xt     = (__hip_bfloat16*)(ws + 9601024);   // 12.85 MB (raw x, resid)
  uint8_t* qkv8          = (uint8_t*)(ws + 22446080);         // 19.3 MB head-major fp8
  uint8_t* ot8           = (uint8_t*)(ws + 60981248);         // 6.4 MB
  __hip_bfloat16* x1t    = (__hip_bfloat16*)(ws + 67403776);  // 12.85 MB
  uint8_t* yt8           = (uint8_t*)(ws + 80248832);         // 6.4 MB (end 86.7 MB)
  uint8_t* h8            = (uint8_t*)(ws + 3178496);          // 25.7 MB overlay (xnt8/xt/qkv8 dead)

  prep_consts<<<dim3(2), dim3(256), 0, stream>>>(bn_g, bn_b, bn_m, bn_v,
                                                 fbn_g, fbn_b, fbn_m, fbn_v, cst);
  cvt_weights<<<dim3(3072), dim3(256), 0, stream>>>(qkv_w, proj_w, fc1_w, fc2_w,
                                                    qkvb8, projb8, fc1b8, fc2b8);
  transpose_x<<<dim3(7, 16, 64), dim3(256), 0, stream>>>(x, xnt8, xt, cst);
  // QKV: M=12544, N=1536, K=512 ; 128x128 -> 98*12 = 1176 blocks ; fp8 head-major out
  gemm1s<0><<<dim3(1176), dim3(256), 0, stream>>>(xnt8, qkvb8, 1536, 512, 12,
                                                  nullptr, qkv8, nullptr, nullptr, nullptr, nullptr);
  attn_kernel<<<dim3(1024), dim3(256), 0, stream>>>(qkv8, ot8);
  // proj: N=512, K=512 ; 98*4 = 392 blocks
  gemm1s<1><<<dim3(392), dim3(256), 0, stream>>>(ot8, projb8, 512, 512, 4,
                                                 x1t, nullptr, nullptr, proj_b, ls1, xt);
  dwconv_tm<<<dim3(1024), dim3(448), 0, stream>>>(x1t, dw_w, cst, yt8);
  // fc1: N=2048, K=512 ; 98*16 = 1568 blocks
  gemm1s<2><<<dim3(1568), dim3(256), 0, stream>>>(yt8, fc1b8, 2048, 512, 16,
                                                  nullptr, h8, nullptr, fc1_b, nullptr, nullptr);
  // fc2: N=512, K=2048 ; 392 blocks ; NCHW fp32 out
  gemm1s<3><<<dim3(392), dim3(256), 0, stream>>>(h8, fc2b8, 512, 2048, 4,
                                                 nullptr, nullptr, (float*)d_out, fc2_b, ls2, x1t);
}

// Round 19
// 195.113 us; speedup vs baseline: 1.2948x; 1.2948x over previous
//
#include <hip/hip_runtime.h>
#include <hip/hip_bf16.h>
#include <hip/hip_fp8.h>
#include <stdint.h>

#define NTOK 196
#define NB   64
#define CCH  512
#define HID  2048
#define MTOT (NB * NTOK)   // 12544

typedef __attribute__((ext_vector_type(8))) short  short8v;
typedef __attribute__((ext_vector_type(4))) float  float4v;
typedef __attribute__((ext_vector_type(2))) int    int2v;

// ---------------- helpers ----------------

__device__ __forceinline__ void mfma_fp8(float4v& d, int2v a, int2v b) {
  asm("v_mfma_f32_16x16x32_fp8_fp8 %0, %1, %2, %0" : "+v"(d) : "v"(a), "v"(b));
}

__device__ __forceinline__ void gload_lds16(const void* gsrc, void* ldst) {
  __builtin_amdgcn_global_load_lds(
      (const __attribute__((address_space(1))) unsigned int*)gsrc,
      (__attribute__((address_space(3))) unsigned int*)ldst, 16, 0, 0);
}

__device__ __forceinline__ int swz4(int r) { return (r ^ (r >> 2)) & 3; }

// hardware packed fp8 conversion: byte0 = fp8(a), byte1 = fp8(b)
__device__ __forceinline__ uint32_t cvt2_fp8(float a, float b) {
  uint32_t d;
  asm("v_cvt_pk_fp8_f32 %0, %1, %2" : "=v"(d) : "v"(a), "v"(b));
  return d;
}

// ---------------- prep: BN constants ----------------

__global__ void prep_consts(const float* __restrict__ bn_g, const float* __restrict__ bn_b,
                            const float* __restrict__ bn_m, const float* __restrict__ bn_v,
                            const float* __restrict__ fbn_g, const float* __restrict__ fbn_b,
                            const float* __restrict__ fbn_m, const float* __restrict__ fbn_v,
                            float* __restrict__ cst) {
  int c = blockIdx.x * blockDim.x + threadIdx.x;
  if (c < CCH) {
    float i1 = bn_g[c] * rsqrtf(bn_v[c] + 1e-5f);
    cst[c] = i1;
    cst[512 + c] = bn_b[c] - bn_m[c] * i1;
    float i2 = fbn_g[c] * rsqrtf(fbn_v[c] + 1e-5f);
    cst[1024 + c] = i2;
    cst[1536 + c] = fbn_b[c] - fbn_m[c] * i2;
  }
}

// ---------------- weights fp32 -> fp8 e4m3, x16 ----------------

__global__ void cvt_weights(const float* __restrict__ qkv_w, const float* __restrict__ proj_w,
                            const float* __restrict__ fc1_w, const float* __restrict__ fc2_w,
                            uint8_t* __restrict__ qkvb, uint8_t* __restrict__ projb,
                            uint8_t* __restrict__ fc1b, uint8_t* __restrict__ fc2b) {
  int i4 = blockIdx.x * blockDim.x + threadIdx.x;    // unit = 4 floats
  const int nq = 1536 * 512 / 4;
  const int np = 512 * 512 / 4;
  const int n1 = 2048 * 512 / 4;
  const float* src;
  uint8_t* dst;
  int k;
  if (i4 < nq)                { src = qkv_w;  dst = qkvb;  k = i4; }
  else if (i4 < nq + np)      { src = proj_w; dst = projb; k = i4 - nq; }
  else if (i4 < nq + np + n1) { src = fc1_w;  dst = fc1b;  k = i4 - nq - np; }
  else                        { src = fc2_w;  dst = fc2b;  k = i4 - nq - np - n1; }
  float4v v = *(const float4v*)(src + 4 * (size_t)k);
  uint32_t w0 = cvt2_fp8(v[0] * 16.0f, v[1] * 16.0f);
  uint32_t w1 = cvt2_fp8(v[2] * 16.0f, v[3] * 16.0f);
  *(uint16_t*)(dst + 4 * (size_t)k)     = (uint16_t)w0;
  *(uint16_t*)(dst + 4 * (size_t)k + 2) = (uint16_t)w1;
}

// ---------------- transpose NCHW fp32 -> token-major: fp8 (BN'd) + bf16 (raw) ----------------

__global__ __launch_bounds__(256) void transpose_x(
    const float* __restrict__ x, uint8_t* __restrict__ xnt8,
    __hip_bfloat16* __restrict__ xt, const float* __restrict__ cst) {
  __shared__ float tile[32][33];
  const int n0 = blockIdx.x * 32;
  const int c0 = blockIdx.y * 32;
  const int b  = blockIdx.z;
  const int j = threadIdx.x & 31, i = threadIdx.x >> 5;
  #pragma unroll
  for (int p = 0; p < 4; ++p) {
    int cc = c0 + i + p * 8;
    int n = n0 + j;
    if (n < NTOK) tile[i + p * 8][j] = x[((size_t)b * CCH + cc) * NTOK + n];
  }
  __syncthreads();
  const float s = cst[c0 + j], t = cst[512 + c0 + j];
  float bn[4];
  size_t off[4];
  bool ok[4];
  #pragma unroll
  for (int p = 0; p < 4; ++p) {
    int n = n0 + i + p * 8;
    int cc = c0 + j;
    ok[p] = (n < NTOK);
    if (ok[p]) {
      float raw = tile[j][i + p * 8];
      size_t o = ((size_t)b * NTOK + n) * CCH + cc;
      xt[o] = __float2bfloat16(raw);
      bn[p] = raw * s + t;
      off[p] = o;
    }
  }
  uint32_t w0 = cvt2_fp8(bn[0], bn[1]);
  uint32_t w1 = cvt2_fp8(bn[2], bn[3]);
  if (ok[0]) xnt8[off[0]] = (uint8_t)w0;
  if (ok[1]) xnt8[off[1]] = (uint8_t)(w0 >> 8);
  if (ok[2]) xnt8[off[2]] = (uint8_t)w1;
  if (ok[3]) xnt8[off[3]] = (uint8_t)(w1 >> 8);
}

// ---------------- fp8 GEMM, R2 schedule: C[M,N] = (A[M,K]*B[N,K]^T)/16 ----------------
// EPI: 0 = qkv: fp8 head-major [sel][h][b][tok][32]
//      1 = proj: x1t = xt + ls1*(v/16+bias)
//      2 = fc1: gelu(v/16+bias)->fp8  3 = fc2: out = x1t + ls2*(v/16+bias) -> NCHW fp32

template<int EPI>
__global__ __launch_bounds__(256, 3) void gemm8f(
    const uint8_t* __restrict__ A, const uint8_t* __restrict__ Bw,
    int N, int K, int NY,
    __hip_bfloat16* __restrict__ outb, uint8_t* __restrict__ out8,
    float* __restrict__ outf,
    const float* __restrict__ bias, const float* __restrict__ ls,
    const __hip_bfloat16* __restrict__ resid) {
  __shared__ char lds[49152];   // 3 bufs x (A 8KB + B 8KB)
  const int tid  = threadIdx.x;
  const int lane = tid & 63;
  const int wave = tid >> 6;

  const int q    = (int)gridDim.x >> 3;
  const int orig = blockIdx.x;
  const int wgid = (orig & 7) * q + (orig >> 3);
  const int bx = wgid / NY;
  const int by = wgid - bx * NY;

  const int m0 = bx * 128;
  const int n0 = by * 128;
  const int wm = (wave >> 1) * 64;
  const int wn = (wave & 1) * 64;
  const int KT = K >> 6;                 // 64-deep K chunks

  float4v acc[4][4] = {};

  auto stage = [&](int buf, int kt) {
    const int kb = kt * 64;
    char* base = lds + buf * 16384;
    #pragma unroll
    for (int i = 0; i < 2; ++i) {
      int L = i * 4096 + tid * 16;
      int row = L >> 6;
      int lc = ((L >> 4) & 3) ^ swz4(row);
      gload_lds16(A + (size_t)(m0 + row) * K + kb + lc * 16, base + L);
    }
    #pragma unroll
    for (int i = 0; i < 2; ++i) {
      int L = i * 4096 + tid * 16;
      int row = L >> 6;
      int lc = ((L >> 4) & 3) ^ swz4(row);
      gload_lds16(Bw + (size_t)(n0 + row) * K + kb + lc * 16, base + 8192 + L);
    }
  };

  auto compute = [&](int buf) {
    const char* bA = lds + buf * 16384;
    const char* bB = bA + 8192;
    const int g = lane >> 4;
    #pragma unroll
    for (int t = 0; t < 2; ++t) {        // two K=32 subtiles per buf
      int2v av[4], bv[4];
      #pragma unroll
      for (int f = 0; f < 4; ++f) {
        int row = wm + f * 16 + (lane & 15);
        int c16 = ((t << 1) | (g >> 1)) ^ swz4(row);
        av[f] = *(const int2v*)(bA + row * 64 + c16 * 16 + (g & 1) * 8);
      }
      #pragma unroll
      for (int j = 0; j < 4; ++j) {
        int row = wn + j * 16 + (lane & 15);
        int c16 = ((t << 1) | (g >> 1)) ^ swz4(row);
        bv[j] = *(const int2v*)(bB + row * 64 + c16 * 16 + (g & 1) * 8);
      }
      #pragma unroll
      for (int i = 0; i < 4; ++i)
        #pragma unroll
        for (int j = 0; j < 4; ++j)
          mfma_fp8(acc[i][j], av[i], bv[j]);
    }
  };

  stage(0, 0);
  stage(1, 1);
  int cur = 0;
  for (int kt = 0; kt < KT - 1; ++kt) {
    asm volatile("s_waitcnt vmcnt(4)" ::: "memory");
    __builtin_amdgcn_s_barrier();
    __builtin_amdgcn_sched_barrier(0);
    if (kt + 2 < KT) {
      int s = cur + 2; if (s >= 3) s -= 3;
      stage(s, kt + 2);
    }
    compute(cur);
    ++cur; if (cur == 3) cur = 0;
  }
  asm volatile("s_waitcnt vmcnt(0)" ::: "memory");
  __builtin_amdgcn_s_barrier();
  __builtin_amdgcn_sched_barrier(0);
  compute(cur);
  asm volatile("s_nop 7\n\ts_nop 7");

  const float RS = 0.0625f;                // undo weight x16

  if (EPI == 0) {
    // fp8 head-major: [sel(3)][h(16)][b(64)][tok(196)][d(32)]
    #pragma unroll
    for (int i = 0; i < 4; ++i)
      #pragma unroll
      for (int j = 0; j < 4; ++j)
        #pragma unroll
        for (int r = 0; r < 4; r += 2) {
          int m = m0 + wm + i * 16 + ((lane >> 4) << 2) + r;
          int n = n0 + wn + j * 16 + (lane & 15);
          int bb = m / NTOK, tok = m - bb * NTOK;
          int bb2 = (m + 1) / NTOK, tok2 = (m + 1) - bb2 * NTOK;
          int sel = n >> 9, hh = (n >> 5) & 15, d = n & 31;
          uint32_t w = cvt2_fp8(acc[i][j][r] * RS, acc[i][j][r + 1] * RS);
          out8[(((size_t)(sel * 16 + hh) * NB + bb) * NTOK + tok) * 32 + d]  = (uint8_t)w;
          out8[(((size_t)(sel * 16 + hh) * NB + bb2) * NTOK + tok2) * 32 + d] = (uint8_t)(w >> 8);
        }
  } else if (EPI == 2) {
    #pragma unroll
    for (int i = 0; i < 4; ++i)
      #pragma unroll
      for (int j = 0; j < 4; ++j)
        #pragma unroll
        for (int r = 0; r < 4; r += 2) {
          int m = m0 + wm + i * 16 + ((lane >> 4) << 2) + r;
          int n = n0 + wn + j * 16 + (lane & 15);
          float z0 = acc[i][j][r] * RS + bias[n];
          float z1 = acc[i][j][r + 1] * RS + bias[n];
          float g0 = z0 / (1.0f + __expf(-1.702f * z0));
          float g1 = z1 / (1.0f + __expf(-1.702f * z1));
          uint32_t w = cvt2_fp8(g0, g1);
          out8[(size_t)m * N + n]       = (uint8_t)w;
          out8[(size_t)(m + 1) * N + n] = (uint8_t)(w >> 8);
        }
  } else if (EPI == 1) {
    #pragma unroll
    for (int i = 0; i < 4; ++i)
      #pragma unroll
      for (int j = 0; j < 4; ++j)
        #pragma unroll
        for (int r = 0; r < 4; ++r) {
          int m = m0 + wm + i * 16 + ((lane >> 4) << 2) + r;
          int n = n0 + wn + j * 16 + (lane & 15);
          float v = acc[i][j][r] * RS + bias[n];
          v = __bfloat162float(resid[(size_t)m * CCH + n]) + ls[n] * v;
          outb[(size_t)m * CCH + n] = __float2bfloat16(v);
        }
  } else {   // EPI == 3 : epilogue + in-LDS transpose -> NCHW fp32
    float* LT = (float*)lds;   // [64][129] fp32 = 33KB
    #pragma unroll 1
    for (int hh = 0; hh < 2; ++hh) {
      __syncthreads();
      if ((wn >> 6) == hh) {
        #pragma unroll
        for (int i = 0; i < 4; ++i)
          #pragma unroll
          for (int j = 0; j < 4; ++j)
            #pragma unroll
            for (int r = 0; r < 4; ++r) {
              int ml = wm + i * 16 + ((lane >> 4) << 2) + r;
              int nl = j * 16 + (lane & 15);
              int n = n0 + wn + nl;
              float v = acc[i][j][r] * RS + bias[n];
              v = __bfloat162float(resid[(size_t)(m0 + ml) * CCH + n]) + ls[n] * v;
              LT[nl * 129 + ml] = v;
            }
      }
      __syncthreads();
      {
        int ml0 = lane << 1;
        int mg = m0 + ml0;
        int bb0 = mg / NTOK;
        int tt0 = mg - bb0 * NTOK;
        int bb1 = (mg + 1) / NTOK;
        int tt1 = (mg + 1) - bb1 * NTOK;
        size_t base0 = (size_t)bb0 * (CCH * NTOK) + tt0;
        size_t base1 = (size_t)bb1 * (CCH * NTOK) + tt1;
        #pragma unroll
        for (int u = 0; u < 16; ++u) {
          int cr = wave * 16 + u;
          int cg = n0 + hh * 64 + cr;
          float v0 = LT[cr * 129 + ml0];
          float v1 = LT[cr * 129 + ml0 + 1];
          outf[base0 + (size_t)cg * NTOK] = v0;
          outf[base1 + (size_t)cg * NTOK] = v1;
        }
      }
    }
  }
}

// ---------------- attention: fp8 end-to-end, head-major input ----------------

__global__ __launch_bounds__(256, 3) void attn_kernel(
    const uint8_t* __restrict__ qkv8, uint8_t* __restrict__ o_t8) {
  __shared__ char sQ[208 * 48];
  __shared__ char sK[224 * 48];
  __shared__ char sV[32 * 240];
  __shared__ char sP[4][16 * 232];
  const int tid  = threadIdx.x;
  const int lane = tid & 63;
  const int wave = tid >> 6;
  const int b = blockIdx.x >> 4;
  const int h = blockIdx.x & 15;
  const size_t CHB = 6272;
  const uint8_t* Qg = qkv8 + ((size_t)(0 * 16 + h) * NB + b) * CHB;
  const uint8_t* Kg = qkv8 + ((size_t)(1 * 16 + h) * NB + b) * CHB;
  const uint8_t* Vg = qkv8 + ((size_t)(2 * 16 + h) * NB + b) * CHB;

  for (int i = tid; i < 144; i += 256) {
    int r = i / 12, w = i % 12;
    ((uint32_t*)(sQ + (196 + r) * 48))[w] = 0u;
  }
  for (int i = tid; i < 336; i += 256) {
    int r = i / 12, w = i % 12;
    ((uint32_t*)(sK + (196 + r) * 48))[w] = 0u;
  }
  for (int i = tid; i < 352; i += 256) {
    int d = i / 11, w = i % 11;
    ((uint32_t*)(sV + d * 240 + 196))[w] = 0u;
  }

  for (int c = tid; c < 392; c += 256) {
    int row = c >> 1, hf = c & 1;
    uint4 vq = *(const uint4*)(Qg + c * 16);
    *(uint4*)(sQ + row * 48 + hf * 16) = vq;
    uint4 vk = *(const uint4*)(Kg + c * 16);
    *(uint4*)(sK + row * 48 + hf * 16) = vk;
  }
  for (int u = tid; u < 784; u += 256) {
    int row = u >> 2, d0 = (u & 3) * 8;
    uint64_t w = *(const uint64_t*)(Vg + (size_t)u * 8);
    #pragma unroll
    for (int e = 0; e < 8; ++e)
      sV[(d0 + e) * 240 + row] = (char)(w >> (8 * e));
  }
  __syncthreads();

  const float scale = 0.17677669529663687f;
  char* Pw = sP[wave];
  const int g = lane >> 4;

  for (int mt = wave; mt < 13; mt += 4) {
    int qrow = mt * 16 + (lane & 15);
    int2v aq = *(const int2v*)(sQ + qrow * 48 + g * 8);

    float4v s[14];
    #pragma unroll
    for (int nt = 0; nt < 14; ++nt) {
      int krow = nt * 16 + (lane & 15);
      int2v bk = *(const int2v*)(sK + krow * 48 + g * 8);
      s[nt] = float4v{0.f, 0.f, 0.f, 0.f};
      mfma_fp8(s[nt], aq, bk);
    }
    asm volatile("s_nop 7\n\ts_nop 7");

    float mx[4] = {-INFINITY, -INFINITY, -INFINITY, -INFINITY};
    #pragma unroll
    for (int nt = 0; nt < 14; ++nt) {
      bool valid = (nt * 16 + (lane & 15)) < NTOK;
      #pragma unroll
      for (int r = 0; r < 4; ++r) {
        float v = valid ? s[nt][r] * scale : -INFINITY;
        s[nt][r] = v;
        mx[r] = fmaxf(mx[r], v);
      }
    }
    #pragma unroll
    for (int off = 1; off < 16; off <<= 1) {
      #pragma unroll
      for (int r = 0; r < 4; ++r) mx[r] = fmaxf(mx[r], __shfl_xor(mx[r], off));
    }
    float sum[4] = {0.f, 0.f, 0.f, 0.f};
    #pragma unroll
    for (int nt = 0; nt < 14; ++nt) {
      #pragma unroll
      for (int r = 0; r < 4; ++r) {
        float e = __expf(s[nt][r] - mx[r]);
        s[nt][r] = e;
        sum[r] += e;
      }
    }
    #pragma unroll
    for (int off = 1; off < 16; off <<= 1) {
      #pragma unroll
      for (int r = 0; r < 4; ++r) sum[r] += __shfl_xor(sum[r], off);
    }
    float rs[4];
    #pragma unroll
    for (int r = 0; r < 4; ++r) rs[r] = 1.0f / sum[r];

    #pragma unroll
    for (int nt = 0; nt < 14; ++nt) {
      int col = nt * 16 + (lane & 15);
      #pragma unroll
      for (int r = 0; r < 4; r += 2) {
        int prow = ((lane >> 4) << 2) + r;
        uint32_t w = cvt2_fp8(s[nt][r], s[nt][r + 1]);
        *(uint8_t*)(Pw + prow * 232 + col)       = (uint8_t)w;
        *(uint8_t*)(Pw + (prow + 1) * 232 + col) = (uint8_t)(w >> 8);
      }
    }

    float4v o0 = float4v{0.f, 0.f, 0.f, 0.f};
    float4v o1 = float4v{0.f, 0.f, 0.f, 0.f};
    #pragma unroll
    for (int ks = 0; ks < 7; ++ks) {
      int2v pa = *(const int2v*)(Pw + (lane & 15) * 232 + ks * 32 + g * 8);
      int2v v0 = *(const int2v*)(sV + (lane & 15) * 240 + ks * 32 + g * 8);
      int2v v1 = *(const int2v*)(sV + (16 + (lane & 15)) * 240 + ks * 32 + g * 8);
      mfma_fp8(o0, pa, v0);
      mfma_fp8(o1, pa, v1);
    }
    asm volatile("s_nop 7\n\ts_nop 7");

    #pragma unroll
    for (int r = 0; r < 4; ++r) {
      int trow = mt * 16 + ((lane >> 4) << 2) + r;
      if (trow < NTOK) {
        size_t ob = ((size_t)b * NTOK + trow) * CCH + h * 32 + (lane & 15);
        uint32_t w = cvt2_fp8(o0[r] * rs[r], o1[r] * rs[r]);
        o_t8[ob]      = (uint8_t)w;
        o_t8[ob + 16] = (uint8_t)(w >> 8);
      }
    }
  }
}

// ---------------- depthwise 7x7 conv, token-major (+BN in, +fBN out, fp8 out) ----------------

__global__ __launch_bounds__(448) void dwconv_tm(
    const __hip_bfloat16* __restrict__ x1t, const float* __restrict__ dw_w,
    const float* __restrict__ cst, uint8_t* __restrict__ yt8) {
  __shared__ float img[196][32];
  __shared__ float wgt[49][32];
  const int tid = threadIdx.x;
  const int b  = blockIdx.x >> 4;
  const int cb = (blockIdx.x & 15) * 32;
  const int c  = tid & 31;
  const int gc = cb + c;
  const float s = cst[gc], t0 = cst[512 + gc];
  #pragma unroll
  for (int k = 0; k < 14; ++k) {
    int p = (tid >> 5) + k * 14;
    img[p][c] = __bfloat162float(x1t[((size_t)b * NTOK + p) * CCH + gc]) * s + t0;
  }
  for (int i = tid; i < 49 * 32; i += 448) {
    int tap = i >> 5, cc = i & 31;
    wgt[tap][cc] = dw_w[(cb + cc) * 49 + tap];
  }
  __syncthreads();

  const int px = tid >> 5;
  float out[14];
  #pragma unroll
  for (int i = 0; i < 14; ++i) out[i] = 0.f;
  #pragma unroll 1
  for (int row = 0; row < 14; ++row) {
    float v[7];
    #pragma unroll
    for (int dx = 0; dx < 7; ++dx) {
      int ix = px + dx - 3;
      v[dx] = ((unsigned)ix < 14u) ? img[row * 14 + ix][c] : 0.f;
    }
    #pragma unroll
    for (int kk = 0; kk < 7; ++kk) {
      int py = row + 3 - kk;
      if (py >= 0 && py < 14) {
        float hsum = 0.f;
        #pragma unroll
        for (int dx = 0; dx < 7; ++dx) hsum = fmaf(v[dx], wgt[kk * 7 + dx][c], hsum);
        out[py] += hsum;
      }
    }
  }
  const float fs = cst[1024 + gc], ft = cst[1536 + gc];
  #pragma unroll
  for (int py = 0; py < 14; py += 2) {
    uint32_t w = cvt2_fp8(out[py] * fs + ft, out[py + 1] * fs + ft);
    yt8[((size_t)b * NTOK + py * 14 + px) * CCH + gc]       = (uint8_t)w;
    yt8[((size_t)b * NTOK + (py + 1) * 14 + px) * CCH + gc] = (uint8_t)(w >> 8);
  }
}

// ---------------- launch ----------------

extern "C" void kernel_launch(void* const* d_in, const int* in_sizes, int n_in,
                              void* d_out, int out_size, void* d_ws, size_t ws_size,
                              hipStream_t stream) {
  const float* x      = (const float*)d_in[0];
  const float* bn_g   = (const float*)d_in[1];
  const float* bn_b   = (const float*)d_in[2];
  const float* bn_m   = (const float*)d_in[3];
  const float* bn_v   = (const float*)d_in[4];
  const float* qkv_w  = (const float*)d_in[5];
  const float* proj_w = (const float*)d_in[6];
  const float* proj_b = (const float*)d_in[7];
  const float* dw_w   = (const float*)d_in[8];
  const float* fbn_g  = (const float*)d_in[9];
  const float* fbn_b  = (const float*)d_in[10];
  const float* fbn_m  = (const float*)d_in[11];
  const float* fbn_v  = (const float*)d_in[12];
  const float* fc1_w  = (const float*)d_in[13];
  const float* fc1_b  = (const float*)d_in[14];
  const float* fc2_w  = (const float*)d_in[15];
  const float* fc2_b  = (const float*)d_in[16];
  const float* ls1    = (const float*)d_in[17];
  const float* ls2    = (const float*)d_in[18];

  char* ws = (char*)d_ws;
  float* cst             = (float*)ws;                        // 8 KB
  uint8_t* qkvb8         = (uint8_t*)(ws + 32768);            // 768 KB
  uint8_t* projb8        = (uint8_t*)(ws + 819200);           // 256 KB
  uint8_t* fc1b8         = (uint8_t*)(ws + 1081344);          // 1 MB
  uint8_t* fc2b8         = (uint8_t*)(ws + 2129920);          // 1 MB
  uint8_t* xnt8          = (uint8_t*)(ws + 3178496);          // 6.4 MB (fp8 BN'd x)
  __hip_bfloat16* xt     = (__hip_bfloat16*)(ws + 9601024);   // 12.85 MB (raw x, resid)
  uint8_t* qkv8          = (uint8_t*)(ws + 22446080);         // 19.3 MB head-major fp8
  uint8_t* ot8           = (uint8_t*)(ws + 60981248);         // 6.4 MB
  __hip_bfloat16* x1t    = (__hip_bfloat16*)(ws + 67403776);  // 12.85 MB
  uint8_t* yt8           = (uint8_t*)(ws + 80248832);         // 6.4 MB (end 86.7 MB)
  uint8_t* h8            = (uint8_t*)(ws + 3178496);          // 25.7 MB overlay (xnt8/xt/qkv8 dead)

  prep_consts<<<dim3(2), dim3(256), 0, stream>>>(bn_g, bn_b, bn_m, bn_v,
                                                 fbn_g, fbn_b, fbn_m, fbn_v, cst);
  cvt_weights<<<dim3(3072), dim3(256), 0, stream>>>(qkv_w, proj_w, fc1_w, fc2_w,
                                                    qkvb8, projb8, fc1b8, fc2b8);
  transpose_x<<<dim3(7, 16, 64), dim3(256), 0, stream>>>(x, xnt8, xt, cst);
  // QKV: M=12544, N=1536, K=512 ; 128x128 -> 98*12 = 1176 blocks ; fp8 head-major out
  gemm8f<0><<<dim3(1176), dim3(256), 0, stream>>>(xnt8, qkvb8, 1536, 512, 12,
                                                  nullptr, qkv8, nullptr, nullptr, nullptr, nullptr);
  attn_kernel<<<dim3(1024), dim3(256), 0, stream>>>(qkv8, ot8);
  // proj: N=512, K=512 ; 98*4 = 392 blocks
  gemm8f<1><<<dim3(392), dim3(256), 0, stream>>>(ot8, projb8, 512, 512, 4,
                                                 x1t, nullptr, nullptr, proj_b, ls1, xt);
  dwconv_tm<<<dim3(1024), dim3(448), 0, stream>>>(x1t, dw_w, cst, yt8);
  // fc1: N=2048, K=512 ; 98*16 = 1568 blocks
  gemm8f<2><<<dim3(1568), dim3(256), 0, stream>>>(yt8, fc1b8, 2048, 512, 16,
                                                  nullptr, h8, nullptr, fc1_b, nullptr, nullptr);
  // fc2: N=512, K=2048 ; 392 blocks ; NCHW fp32 out
  gemm8f<3><<<dim3(392), dim3(256), 0, stream>>>(h8, fc2b8, 512, 2048, 4,
                                                 nullptr, nullptr, (float*)d_out, fc2_b, ls2, x1t);
}